// Round 6
// baseline (232.182 us; speedup 1.0000x reference)
//
#include <hip/hip_runtime.h>
#include <math.h>

// dims
#define B_   64
#define P_   8
#define N1_  1152
#define N2_  128
#define D_   16

#define NSPLIT 16                      // i-splits for k1/k3c partials
#define CHUNK  (N1_ / NSPLIT)          // 72 i per chunk
#define NIB    (CHUNK / 4)             // 18 i-blocks of 4

typedef __attribute__((ext_vector_type(8)))  short bf16x8;
typedef __attribute__((ext_vector_type(4)))  float f32x4;
typedef __attribute__((ext_vector_type(16))) float f32x16;

// split 8 fp32 into hi/lo bf16 fragments (hi = truncate, lo = bf16(w - hi))
__device__ inline void split_frag(float4 a0, float4 a1, bf16x8& hi, bf16x8& lo)
{
    float w[8] = {a0.x, a0.y, a0.z, a0.w, a1.x, a1.y, a1.z, a1.w};
#pragma unroll
    for (int j = 0; j < 8; ++j) {
        unsigned ub = __float_as_uint(w[j]);
        hi[j] = (short)(ub >> 16);
        float hif = __uint_as_float(ub & 0xffff0000u);
        float r = w[j] - hif;
        lo[j] = (short)(__float_as_uint(r) >> 16);
    }
}

__device__ inline void split_arr(const float* w, bf16x8& hi, bf16x8& lo)
{
#pragma unroll
    for (int j = 0; j < 8; ++j) {
        unsigned ub = __float_as_uint(w[j]);
        hi[j] = (short)(ub >> 16);
        float hif = __uint_as_float(ub & 0xffff0000u);
        float r = w[j] - hif;
        lo[j] = (short)(__float_as_uint(r) >> 16);
    }
}

// pack 4 fp32 into hi/lo bf16 uint2 (same split formula — bit-identical frags)
__device__ inline void split4_pack(float4 s, uint2& hp, uint2& lp)
{
    float w[4] = {s.x, s.y, s.z, s.w};
    unsigned hs[4], ls[4];
#pragma unroll
    for (int j = 0; j < 4; ++j) {
        unsigned ub = __float_as_uint(w[j]);
        hs[j] = ub >> 16;
        float hif = __uint_as_float(ub & 0xffff0000u);
        float r = w[j] - hif;
        ls[j] = __float_as_uint(r) >> 16;
    }
    hp.x = hs[0] | (hs[1] << 16); hp.y = hs[2] | (hs[3] << 16);
    lp.x = ls[0] | (ls[1] << 16); lp.y = ls[2] | (ls[3] << 16);
}

// round fp32 -> bf16 bits (RNE), and the dequantized fp32 value
__device__ inline unsigned short bf16_rne(float x, float& deq)
{
    unsigned ub = __float_as_uint(x);
    unsigned r  = ub + 0x7fffu + ((ub >> 16) & 1u);
    unsigned short us = (unsigned short)(r >> 16);
    deq = __uint_as_float(((unsigned)us) << 16);
    return us;
}

// ---------------------------------------------------------------------------
// K1 (MFMA): s0p[isp][b][n][d] = sum_{i in chunk, p} W[i,n,d,p]*x[b,i,p]
// Wave = one n, loop over 4 b-tiles. x read DIRECTLY from [b][i][p] layout
// (2.4 MB, L2-resident after first touch) with in-loop split — bit-identical
// fragments to the old pre-split planes (same formula). No k0 dependency.
// ---------------------------------------------------------------------------
__global__ __launch_bounds__(256) void k1_s0_mfma(const float* __restrict__ x,
                                                  const float* __restrict__ W,
                                                  float* __restrict__ s0p)
{
    const int tid   = threadIdx.x;
    const int lane  = tid & 63;
    const int wv    = tid >> 6;
    const int col   = lane & 15;
    const int quad  = lane >> 4;
    const int n     = blockIdx.x * 4 + wv;
    const int isp   = blockIdx.y;
    const int ibase = isp * CHUNK;

    f32x4 acc[4];
#pragma unroll
    for (int bt = 0; bt < 4; ++bt) acc[bt] = (f32x4){0.f, 0.f, 0.f, 0.f};

    for (int ib = 0; ib < NIB; ++ib) {
        const int iq = ibase + ib * 4 + quad;
        const float* wp = W + ((size_t)iq * N2_ + n) * (D_ * P_) + col * P_;
        float4 wa = *(const float4*)wp;
        float4 wb = *(const float4*)(wp + 4);
        bf16x8 ahi, alo;
        split_frag(wa, wb, ahi, alo);
#pragma unroll
        for (int bt = 0; bt < 4; ++bt) {
            const int b = bt * 16 + col;
            const float* xp = x + ((size_t)b * N1_ + iq) * P_;
            float4 xa = *(const float4*)xp;
            float4 xb = *(const float4*)(xp + 4);
            bf16x8 bhi, blo;
            split_frag(xa, xb, bhi, blo);
            acc[bt] = __builtin_amdgcn_mfma_f32_16x16x32_bf16(ahi, bhi, acc[bt], 0, 0, 0);
            acc[bt] = __builtin_amdgcn_mfma_f32_16x16x32_bf16(ahi, blo, acc[bt], 0, 0, 0);
            acc[bt] = __builtin_amdgcn_mfma_f32_16x16x32_bf16(alo, bhi, acc[bt], 0, 0, 0);
        }
    }
#pragma unroll
    for (int bt = 0; bt < 4; ++bt) {
        const int b = bt * 16 + col;
        float4 v = make_float4(acc[bt][0], acc[bt][1], acc[bt][2], acc[bt][3]);
        *(float4*)(s0p + (size_t)isp * (B_ * N2_ * D_) + (size_t)b * (N2_ * D_)
                   + n * D_ + quad * 4) = v;
    }
}

// ---------------------------------------------------------------------------
// K2/K5: reduce nsplit partials (float4), scale, squash over d (16), write v.
// For the v0 call, also emit pre-split bf16 hi/lo planes for k3a2.
// ---------------------------------------------------------------------------
__global__ __launch_bounds__(256) void k2_squash(const float* __restrict__ spart,
                                                 float* __restrict__ vout,
                                                 unsigned short* __restrict__ v0h,
                                                 unsigned short* __restrict__ v0l,
                                                 float scale, int nsplit)
{
    int idx = blockIdx.x * 256 + threadIdx.x;   // float4 index, 0..32767
    float4 s = make_float4(0.f, 0.f, 0.f, 0.f);
    for (int sp = 0; sp < nsplit; ++sp) {
        float4 t = *(const float4*)(spart + (size_t)sp * (B_ * N2_ * D_) + (size_t)idx * 4);
        s.x += t.x; s.y += t.y; s.z += t.z; s.w += t.w;
    }
    s.x *= scale; s.y *= scale; s.z *= scale; s.w *= scale;
    float sq = s.x * s.x + s.y * s.y + s.z * s.z + s.w * s.w;
    sq += __shfl_xor(sq, 1);
    sq += __shfl_xor(sq, 2);
    float norm = sqrtf(sq + 1.1920929e-7f);
    float f = (sq / (1.f + sq)) / norm;
    float4 o = make_float4(s.x * f, s.y * f, s.z * f, s.w * f);
    *(float4*)(vout + (size_t)idx * 4) = o;
    if (v0h) {
        uint2 hp, lp;
        split4_pack(o, hp, lp);
        *(uint2*)(v0h + (size_t)idx * 4) = hp;
        *(uint2*)(v0l + (size_t)idx * 4) = lp;
    }
}

// ---------------------------------------------------------------------------
// K3A2 (MFMA 32x32x16, fused exp + denominator), 1024-thread blocks:
// one block per i-quad; 16 waves cover ALL 128 n (wave wv -> n = wv*8+nt).
// Denominator is block-local: LDS reduce over the 16 waves, plain store to
// denom[i][b] (exactly one writer) — no atomics, no zero-init pass.
//   e_t[i][n][b] = bf16_rne( exp( sum_d v0[b,n,d]*pred[b,i,n,d] ) )
//   denom[i][b]  = sum_n dequant(e_t)   (summed over rounded values)
// ---------------------------------------------------------------------------
__global__ __launch_bounds__(1024) void k3a2_mfma32(const float* __restrict__ x,
                                                    const float* __restrict__ W,
                                                    const unsigned short* __restrict__ v0h,
                                                    const unsigned short* __restrict__ v0l,
                                                    unsigned short* __restrict__ e_t,
                                                    float* __restrict__ denom)
{
    const int tid  = threadIdx.x;
    const int lane = tid & 63;
    const int wv   = tid >> 6;          // 0..15
    const int m    = lane & 31;
    const int kh   = lane >> 5;         // d-half in MFMA / p-half in epilogue
    const int isub = m >> 3;
    const int p    = m & 7;
    const int i0   = blockIdx.x * 4;    // this block's 4 i's
    const int nbase = wv * 8;

    // x fragments, loaded once from [b][i][p]: xq0[is]=x[b=m][i0+is][kh*4..],
    // xq1: b=32+m.  (64 scattered 16-B lane loads; x is L2-hot, tiny volume.)
    float4 xq0[4], xq1[4];
#pragma unroll
    for (int is = 0; is < 4; ++is) {
        xq0[is] = *(const float4*)(x + ((size_t)m * N1_ + i0 + is) * P_ + kh * 4);
        xq1[is] = *(const float4*)(x + ((size_t)(32 + m) * N1_ + i0 + is) * P_ + kh * 4);
    }

    float dacc[4] = {0.f, 0.f, 0.f, 0.f};

#pragma unroll 1
    for (int nt = 0; nt < 8; ++nt) {
        const int n = nbase + nt;

        // B fragments: v0 for 2 b-tiles of 32 (pre-split bf16, 16B each)
        bf16x8 vhi[2], vlo[2];
#pragma unroll
        for (int bt = 0; bt < 2; ++bt) {
            const size_t vo = (size_t)(bt * 32 + m) * (N2_ * D_) + n * D_ + kh * 8;
            vhi[bt] = *(const bf16x8*)(v0h + vo);
            vlo[bt] = *(const bf16x8*)(v0l + vo);
        }

        // A fragment: W gather, 8 dwords stride 32 B
        const float* wp = W + ((size_t)(i0 + isub) * N2_ + n) * (D_ * P_) + kh * 64 + p;
        float a[8];
#pragma unroll
        for (int j = 0; j < 8; ++j) a[j] = wp[8 * j];
        bf16x8 ahi, alo;
        split_arr(a, ahi, alo);

        f32x16 acc0, acc1;
#pragma unroll
        for (int r = 0; r < 16; ++r) { acc0[r] = 0.f; acc1[r] = 0.f; }
        acc0 = __builtin_amdgcn_mfma_f32_32x32x16_bf16(ahi, vhi[0], acc0, 0, 0, 0);
        acc0 = __builtin_amdgcn_mfma_f32_32x32x16_bf16(ahi, vlo[0], acc0, 0, 0, 0);
        acc0 = __builtin_amdgcn_mfma_f32_32x32x16_bf16(alo, vhi[0], acc0, 0, 0, 0);
        acc1 = __builtin_amdgcn_mfma_f32_32x32x16_bf16(ahi, vhi[1], acc1, 0, 0, 0);
        acc1 = __builtin_amdgcn_mfma_f32_32x32x16_bf16(ahi, vlo[1], acc1, 0, 0, 0);
        acc1 = __builtin_amdgcn_mfma_f32_32x32x16_bf16(alo, vhi[1], acc1, 0, 0, 0);

#pragma unroll
        for (int is = 0; is < 4; ++is) {
            float r0 = acc0[4 * is] * xq0[is].x + acc0[4 * is + 1] * xq0[is].y
                     + acc0[4 * is + 2] * xq0[is].z + acc0[4 * is + 3] * xq0[is].w;
            float r1 = acc1[4 * is] * xq1[is].x + acc1[4 * is + 1] * xq1[is].y
                     + acc1[4 * is + 2] * xq1[is].z + acc1[4 * is + 3] * xq1[is].w;
            r0 += __shfl_xor(r0, 32);           // sum the two p-halves
            r1 += __shfl_xor(r1, 32);
            float e = __expf(kh ? r1 : r0);     // lane(m,kh) owns b = kh*32+m
            float er;
            unsigned short eb = bf16_rne(e, er);
            e_t[(size_t)(i0 + is) * (N2_ * 64) + n * 64 + kh * 32 + m] = eb;
            dacc[is] += er;
        }
    }

    // block-local exp-sum over all 128 n (16 waves), plain store (one writer)
    __shared__ float dred[16][4][64];
#pragma unroll
    for (int is = 0; is < 4; ++is) dred[wv][is][kh * 32 + m] = dacc[is];
    __syncthreads();
    if (tid < 256) {
        const int is = tid >> 6;
        const int b  = tid & 63;
        float s = 0.f;
#pragma unroll
        for (int w = 0; w < 16; ++w) s += dred[w][is][b];
        denom[(size_t)(i0 + is) * 64 + b] = s;
    }
}

// ---------------------------------------------------------------------------
// K3C (MFMA): s1p[isp][b][n][d] = sum_{i,p} W[i,n,d,p]*c[b,i,n]*x[b,i,p]
// c = dequant(e_t) * rcp(denom[i,b]); x read directly from [b][i][p].
// ---------------------------------------------------------------------------
__global__ __launch_bounds__(256) void k3c_s1_mfma(const float* __restrict__ x,
                                                   const float* __restrict__ W,
                                                   const unsigned short* __restrict__ e_t,
                                                   const float* __restrict__ denom,
                                                   float* __restrict__ s1p)
{
    const int tid   = threadIdx.x;
    const int lane  = tid & 63;
    const int wv    = tid >> 6;
    const int col   = lane & 15;
    const int quad  = lane >> 4;
    const int n     = blockIdx.x * 4 + wv;
    const int isp   = blockIdx.y;
    const int ibase = isp * CHUNK;

    f32x4 acc[4];
#pragma unroll
    for (int bt = 0; bt < 4; ++bt) acc[bt] = (f32x4){0.f, 0.f, 0.f, 0.f};

    for (int ib = 0; ib < NIB; ++ib) {
        const int iq = ibase + ib * 4 + quad;
        const float* wp = W + ((size_t)iq * N2_ + n) * (D_ * P_) + col * P_;
        float4 wa = *(const float4*)wp;
        float4 wb = *(const float4*)(wp + 4);
        bf16x8 ahi, alo;
        split_frag(wa, wb, ahi, alo);
#pragma unroll
        for (int bt = 0; bt < 4; ++bt) {
            const int b = bt * 16 + col;
            const float* xp = x + ((size_t)b * N1_ + iq) * P_;
            float4 xa = *(const float4*)xp;
            float4 xb = *(const float4*)(xp + 4);
            float e  = __uint_as_float((unsigned)e_t[((size_t)iq * N2_ + n) * 64 + b] << 16);
            float dv = denom[(size_t)iq * 64 + b];
            float c  = e * __builtin_amdgcn_rcpf(dv);
            float4 ya = make_float4(xa.x * c, xa.y * c, xa.z * c, xa.w * c);
            float4 yb = make_float4(xb.x * c, xb.y * c, xb.z * c, xb.w * c);
            bf16x8 bhi, blo;
            split_frag(ya, yb, bhi, blo);
            acc[bt] = __builtin_amdgcn_mfma_f32_16x16x32_bf16(ahi, bhi, acc[bt], 0, 0, 0);
            acc[bt] = __builtin_amdgcn_mfma_f32_16x16x32_bf16(ahi, blo, acc[bt], 0, 0, 0);
            acc[bt] = __builtin_amdgcn_mfma_f32_16x16x32_bf16(alo, bhi, acc[bt], 0, 0, 0);
        }
    }
#pragma unroll
    for (int bt = 0; bt < 4; ++bt) {
        const int b = bt * 16 + col;
        float4 v = make_float4(acc[bt][0], acc[bt][1], acc[bt][2], acc[bt][3]);
        *(float4*)(s1p + (size_t)isp * (B_ * N2_ * D_) + (size_t)b * (N2_ * D_)
                   + n * D_ + quad * 4) = v;
    }
}

// ---------------------------------------------------------------------------
extern "C" void kernel_launch(void* const* d_in, const int* in_sizes, int n_in,
                              void* d_out, int out_size, void* d_ws, size_t ws_size,
                              hipStream_t stream)
{
    const float* x = (const float*)d_in[0];   // [64,1152,8]
    const float* W = (const float*)d_in[1];   // [1152,128,16,8]
    float* out = (float*)d_out;               // [64,128,16]

    float* s_part = (float*)d_ws;                               // 16*131072 floats (8.4 MB)
    float* v0     = s_part + (size_t)NSPLIT * B_ * N2_ * D_;    // 131072 floats
    float* denom  = v0 + B_ * N2_ * D_;                         // 73728 floats: [i][b]
    unsigned short* v0h = (unsigned short*)(denom + (size_t)N1_ * 64);   // 131072 bf16
    unsigned short* v0l = v0h + (size_t)B_ * N2_ * D_;                   // 131072 bf16
    unsigned short* e_t = v0l + (size_t)B_ * N2_ * D_;                   // 9437184 bf16: exp(raw), [i][n][b]

    k1_s0_mfma  <<<dim3(32, NSPLIT),  256, 0, stream>>>(x, W, s_part);
    k2_squash   <<<128,               256, 0, stream>>>(s_part, v0, v0h, v0l, 1.f / 128.f, NSPLIT);
    k3a2_mfma32 <<<N1_ / 4,          1024, 0, stream>>>(x, W, v0h, v0l, e_t, denom);
    k3c_s1_mfma <<<dim3(32, NSPLIT),  256, 0, stream>>>(x, W, e_t, denom, s_part);
    k2_squash   <<<128,               256, 0, stream>>>(s_part, out, nullptr, nullptr, 1.f, NSPLIT);
}